// Round 2
// baseline (71.512 us; speedup 1.0000x reference)
//
#include <hip/hip_runtime.h>

#define N_SAMPLES 64
#define M_ELEMS   307200            // 480*640 per-sample elements
#define M4        (M_ELEMS / 4)     // 76800 float4 per sample
#define BLOCK     256
#define BPS       30                // blocks per sample
#define TPS       (BPS * BLOCK)     // 7680 threads per sample
#define ITERS     (M4 / TPS)        // exactly 10, no tail

__device__ __forceinline__ float wave_reduce_max(float v) {
    #pragma unroll
    for (int off = 32; off > 0; off >>= 1)
        v = fmaxf(v, __shfl_down(v, off, 64));
    return v;
}

__device__ __forceinline__ float wave_reduce_sum(float v) {
    #pragma unroll
    for (int off = 32; off > 0; off >>= 1)
        v += __shfl_down(v, off, 64);
    return v;
}

// Pass 1: per-sample max of |pred - targ|
__global__ __launch_bounds__(BLOCK, 4) void berhu_max_kernel(
        const float* __restrict__ pred,
        const float* __restrict__ targ,
        unsigned int* __restrict__ maxbits) {
    const int n = blockIdx.y;
    const float4* p = (const float4*)(pred + (size_t)n * M_ELEMS);
    const float4* t = (const float4*)(targ + (size_t)n * M_ELEMS);
    const int i0 = blockIdx.x * BLOCK + threadIdx.x;

    // Issue all 20 loads before consuming — static indices keep these in VGPRs.
    float4 a[ITERS], b[ITERS];
    #pragma unroll
    for (int k = 0; k < ITERS; ++k) {
        a[k] = p[i0 + k * TPS];
        b[k] = t[i0 + k * TPS];
    }

    float m = 0.0f;
    #pragma unroll
    for (int k = 0; k < ITERS; ++k) {
        m = fmaxf(m, fabsf(a[k].x - b[k].x));
        m = fmaxf(m, fabsf(a[k].y - b[k].y));
        m = fmaxf(m, fabsf(a[k].z - b[k].z));
        m = fmaxf(m, fabsf(a[k].w - b[k].w));
    }

    m = wave_reduce_max(m);
    __shared__ float smax[BLOCK / 64];
    const int wid  = threadIdx.x >> 6;
    const int lane = threadIdx.x & 63;
    if (lane == 0) smax[wid] = m;
    __syncthreads();
    if (threadIdx.x == 0) {
        float bm = smax[0];
        #pragma unroll
        for (int w = 1; w < BLOCK / 64; ++w) bm = fmaxf(bm, smax[w]);
        // |d| >= 0, so uint bit-pattern compare == float compare
        atomicMax(&maxbits[n], __float_as_uint(bm));
    }
}

// Pass 2: per-sample BerHu sum, scaled and atomically accumulated into out[0]
__global__ __launch_bounds__(BLOCK, 4) void berhu_sum_kernel(
        const float* __restrict__ pred,
        const float* __restrict__ targ,
        const unsigned int* __restrict__ maxbits,
        float* __restrict__ out) {
    const int n = blockIdx.y;
    const float c = __uint_as_float(maxbits[n]) * 0.2f;   // max/5
    const float c2 = c * c;
    const float inv2c = (c > 0.0f) ? (0.5f / c) : 0.0f;

    const float4* p = (const float4*)(pred + (size_t)n * M_ELEMS);
    const float4* t = (const float4*)(targ + (size_t)n * M_ELEMS);
    const int i0 = blockIdx.x * BLOCK + threadIdx.x;

    float4 a[ITERS], b[ITERS];
    #pragma unroll
    for (int k = 0; k < ITERS; ++k) {
        a[k] = p[i0 + k * TPS];
        b[k] = t[i0 + k * TPS];
    }

    float s = 0.0f;
    #pragma unroll
    for (int k = 0; k < ITERS; ++k) {
        float d, ad;
        d = a[k].x - b[k].x; ad = fabsf(d); s += (ad <= c) ? ad : (d * d + c2) * inv2c;
        d = a[k].y - b[k].y; ad = fabsf(d); s += (ad <= c) ? ad : (d * d + c2) * inv2c;
        d = a[k].z - b[k].z; ad = fabsf(d); s += (ad <= c) ? ad : (d * d + c2) * inv2c;
        d = a[k].w - b[k].w; ad = fabsf(d); s += (ad <= c) ? ad : (d * d + c2) * inv2c;
    }

    s = wave_reduce_sum(s);
    __shared__ float ssum[BLOCK / 64];
    const int wid  = threadIdx.x >> 6;
    const int lane = threadIdx.x & 63;
    if (lane == 0) ssum[wid] = s;
    __syncthreads();
    if (threadIdx.x == 0) {
        float bs = ssum[0];
        #pragma unroll
        for (int w = 1; w < BLOCK / 64; ++w) bs += ssum[w];
        // fold both means into the scale; one atomic per block
        atomicAdd(out, bs * (1.0f / ((float)M_ELEMS * (float)N_SAMPLES)));
    }
}

extern "C" void kernel_launch(void* const* d_in, const int* in_sizes, int n_in,
                              void* d_out, int out_size, void* d_ws, size_t ws_size,
                              hipStream_t stream) {
    const float* pred = (const float*)d_in[0];
    const float* targ = (const float*)d_in[1];
    float* out = (float*)d_out;

    unsigned int* maxbits = (unsigned int*)d_ws;

    // ws/out poisoned 0xAA and NOT re-poisoned between replays — zero every call.
    hipMemsetAsync(d_ws, 0, N_SAMPLES * sizeof(unsigned int), stream);
    hipMemsetAsync(d_out, 0, sizeof(float), stream);

    dim3 grid(BPS, N_SAMPLES);
    berhu_max_kernel<<<grid, BLOCK, 0, stream>>>(pred, targ, maxbits);
    berhu_sum_kernel<<<grid, BLOCK, 0, stream>>>(pred, targ, maxbits, out);
}